// Round 3
// baseline (4484.458 us; speedup 1.0000x reference)
//
#include <hip/hip_runtime.h>
#include <hip/hip_bf16.h>

typedef __bf16 bf16x8 __attribute__((ext_vector_type(8)));
typedef float f32x4 __attribute__((ext_vector_type(4)));

__device__ inline bf16x8 cvt8(const float* p) {
    float4 a = *(const float4*)p;
    float4 b = *(const float4*)(p + 4);
    bf16x8 r;
    r[0] = (__bf16)a.x; r[1] = (__bf16)a.y; r[2] = (__bf16)a.z; r[3] = (__bf16)a.w;
    r[4] = (__bf16)b.x; r[5] = (__bf16)b.y; r[6] = (__bf16)b.z; r[7] = (__bf16)b.w;
    return r;
}

// ---------------------------------------------------------------------------
// GEMM: C[m,n] = sum_k A[m,k] * B[n,k]   (fp32 in, bf16 out)
// A: [M,K] f32 row-major, B: [N,K] f32 row-major, C: [M,N] bf16 row-major.
// One wave computes a 16x64 strip: 4 accumulators, A-frag reused 4x.
// MFMA 16x16x32 bf16: A-frag A[m=lane&15][k=quad*8+j], B-frag likewise from
// B^T rows; C/D: col=lane&15, row=quad*4+reg.
// ---------------------------------------------------------------------------
__global__ __launch_bounds__(256) void gemm_bt(const float* __restrict__ A,
                                               const float* __restrict__ B,
                                               __hip_bfloat16* __restrict__ C,
                                               int M, int N, int K) {
    int wave = blockIdx.x * 4 + (threadIdx.x >> 6);
    int lane = threadIdx.x & 63;
    int tilesN = N >> 6;                 // 64-wide strips
    int tm = wave / tilesN;
    int tn = wave - tm * tilesN;
    int quad = lane >> 4;
    int l16  = lane & 15;

    const float* a_ptr = A + (size_t)(tm * 16 + l16) * K + quad * 8;
    const float* b_ptr = B + (size_t)(tn * 64 + l16) * K + quad * 8;

    f32x4 acc[4] = {{0.f,0.f,0.f,0.f},{0.f,0.f,0.f,0.f},
                    {0.f,0.f,0.f,0.f},{0.f,0.f,0.f,0.f}};

    for (int k = 0; k < K; k += 32) {
        bf16x8 av = cvt8(a_ptr + k);
#pragma unroll
        for (int t = 0; t < 4; ++t) {
            bf16x8 bv = cvt8(b_ptr + (size_t)t * 16 * K + k);
            acc[t] = __builtin_amdgcn_mfma_f32_16x16x32_bf16(av, bv, acc[t], 0, 0, 0);
        }
    }

#pragma unroll
    for (int t = 0; t < 4; ++t) {
#pragma unroll
        for (int r = 0; r < 4; ++r) {
            int row = tm * 16 + quad * 4 + r;
            int col = tn * 64 + t * 16 + l16;
            C[(size_t)row * N + col] = __float2bfloat16(acc[t][r]);
        }
    }
}

// ---------------------------------------------------------------------------
// Causal GQA attention. One wave per (b, h, query-row). Lanes parallel over
// 64 keys per chunk; online softmax; V-accum with lanes over head-dim (2/lane).
// Output written as FP32 (reference output dtype).
// ---------------------------------------------------------------------------
__global__ __launch_bounds__(256) void attn_kernel(const __hip_bfloat16* __restrict__ Q,
                                                   const __hip_bfloat16* __restrict__ Kb,
                                                   const __hip_bfloat16* __restrict__ Vb,
                                                   float* __restrict__ O) {
    const int T = 2048, DKV = 512, C = 2048;
    int w = threadIdx.x >> 6;
    int lane = threadIdx.x & 63;

    int bg = blockIdx.x & 7;          // (b,g): 8 K/V sets, aligned with XCD id
    int hq = (blockIdx.x >> 3) & 3;   // query head within group
    int rb = blockIdx.x >> 5;         // row block (512 of them)
    int row = rb * 4 + w;
    int b = bg >> 2, g = bg & 3;
    int h = g * 4 + hq;

    __shared__ float qs[4][128];

    const __hip_bfloat16* qrow = Q + ((size_t)b * T + row) * C + h * 128;
    {
        float2 qf = __bfloat1622float2(*(const __hip_bfloat162*)(qrow + 2 * lane));
        const float scale = 0.08838834764831845f;  // 128^-0.5
        qs[w][2 * lane]     = qf.x * scale;
        qs[w][2 * lane + 1] = qf.y * scale;
    }
    __syncthreads();

    float m = -1e30f, l = 0.f, o0 = 0.f, o1 = 0.f;
    const __hip_bfloat16* kbase = Kb + (size_t)b * T * DKV + g * 128;
    const __hip_bfloat16* vbase = Vb + (size_t)b * T * DKV + g * 128 + 2 * lane;

    int nch = (row >> 6) + 1;
    for (int ch = 0; ch < nch; ++ch) {
        int j0 = ch << 6;
        // --- scores: lane handles key j0+lane ---
        const __hip_bfloat16* krow = kbase + (size_t)(j0 + lane) * DKV;
        float s = 0.f;
#pragma unroll
        for (int d = 0; d < 128; d += 8) {
            bf16x8 kv8 = *(const bf16x8*)(krow + d);
#pragma unroll
            for (int e = 0; e < 8; ++e)
                s += qs[w][d + e] * (float)kv8[e];
        }
        s = (j0 + lane <= row) ? s : -1e30f;

        // --- online softmax ---
        float cmax = s;
#pragma unroll
        for (int off = 32; off; off >>= 1)
            cmax = fmaxf(cmax, __shfl_xor(cmax, off));
        float mnew = fmaxf(m, cmax);
        float p = __expf(s - mnew);
        float ps = p;
#pragma unroll
        for (int off = 32; off; off >>= 1)
            ps += __shfl_xor(ps, off);
        float alpha = __expf(m - mnew);
        l = l * alpha + ps;
        o0 *= alpha; o1 *= alpha;

        // --- o += P * V  (lanes over head-dim, coalesced) ---
        const __hip_bfloat16* vrow = vbase + (size_t)j0 * DKV;
#pragma unroll 8
        for (int j = 0; j < 64; ++j) {
            float pj = __shfl(p, j);
            float2 vf = __bfloat1622float2(*(const __hip_bfloat162*)(vrow + (size_t)j * DKV));
            o0 += pj * vf.x;
            o1 += pj * vf.y;
        }
        m = mnew;
    }

    float inv = 1.f / l;
    float* orow = O + ((size_t)b * T + row) * C + h * 128;
    *(float2*)(orow + 2 * lane) = make_float2(o0 * inv, o1 * inv);
}

extern "C" void kernel_launch(void* const* d_in, const int* in_sizes, int n_in,
                              void* d_out, int out_size, void* d_ws, size_t ws_size,
                              hipStream_t stream) {
    const float* x  = (const float*)d_in[0];   // [2,2048,2048] fp32
    const float* Wq = (const float*)d_in[1];   // [2048,2048] fp32
    const float* Wk = (const float*)d_in[2];   // [512,2048] fp32
    const float* Wv = (const float*)d_in[3];   // [512,2048] fp32
    float* out = (float*)d_out;                // [2,2048,2048] fp32

    const int M = 4096;   // b*t
    const int Kd = 2048;  // d_model
    __hip_bfloat16* Qb = (__hip_bfloat16*)d_ws;                  // [4096,2048] bf16
    __hip_bfloat16* Kbuf = Qb + (size_t)M * 2048;                // [4096,512]  bf16
    __hip_bfloat16* Vbuf = Kbuf + (size_t)M * 512;               // [4096,512]  bf16

    // Q/K/V projections: x @ W.T  (fp32 in, bf16 out)
    gemm_bt<<<(M / 16) * (2048 / 64) / 4, 256, 0, stream>>>(x, Wq, Qb, M, 2048, Kd);
    gemm_bt<<<(M / 16) * (512 / 64) / 4, 256, 0, stream>>>(x, Wk, Kbuf, M, 512, Kd);
    gemm_bt<<<(M / 16) * (512 / 64) / 4, 256, 0, stream>>>(x, Wv, Vbuf, M, 512, Kd);

    // causal GQA attention: 8 (b,g) * 4 hq * 512 row-blocks = 16384 blocks
    attn_kernel<<<16384, 256, 0, stream>>>(Qb, Kbuf, Vbuf, out);
}

// Round 4
// 668.261 us; speedup vs baseline: 6.7106x; 6.7106x over previous
//
#include <hip/hip_runtime.h>
#include <hip/hip_bf16.h>

typedef __bf16 bf16x8 __attribute__((ext_vector_type(8)));
typedef float f32x4 __attribute__((ext_vector_type(4)));

#define MFMA16(a, b, c) __builtin_amdgcn_mfma_f32_16x16x32_bf16(a, b, c, 0, 0, 0)

__device__ inline unsigned int pack_bf16(float a, float b) {
    unsigned short ua = __builtin_bit_cast(unsigned short, (__bf16)a);
    unsigned short ub = __builtin_bit_cast(unsigned short, (__bf16)b);
    return ((unsigned int)ub << 16) | ua;
}

// ---------------------------------------------------------------------------
// fp32 -> bf16 conversion (each element converted exactly once)
// ---------------------------------------------------------------------------
__global__ void cvt_f32_bf16(const float* __restrict__ in,
                             __hip_bfloat16* __restrict__ out, int n) {
    int i = (blockIdx.x * blockDim.x + threadIdx.x) * 8;
    if (i >= n) return;
    float4 a = *(const float4*)(in + i);
    float4 b = *(const float4*)(in + i + 4);
    bf16x8 r;
    r[0] = (__bf16)a.x; r[1] = (__bf16)a.y; r[2] = (__bf16)a.z; r[3] = (__bf16)a.w;
    r[4] = (__bf16)b.x; r[5] = (__bf16)b.y; r[6] = (__bf16)b.z; r[7] = (__bf16)b.w;
    *(bf16x8*)((__bf16*)out + i) = r;
}

// ---------------------------------------------------------------------------
// bf16 GEMM: C[m,n] = scale * sum_k A[m,k]*B[n,k]. Wave: 16x64 strip.
// ---------------------------------------------------------------------------
__global__ __launch_bounds__(256) void gemm_bt_bf16(const __hip_bfloat16* __restrict__ A,
                                                    const __hip_bfloat16* __restrict__ B,
                                                    __hip_bfloat16* __restrict__ C,
                                                    int M, int N, int K, float scale) {
    int wave = blockIdx.x * 4 + (threadIdx.x >> 6);
    int lane = threadIdx.x & 63;
    int tilesN = N >> 6;
    int tm = wave / tilesN;
    int tn = wave - tm * tilesN;
    int quad = lane >> 4;
    int l16  = lane & 15;

    const __bf16* a_ptr = (const __bf16*)A + (size_t)(tm * 16 + l16) * K + quad * 8;
    const __bf16* b_ptr = (const __bf16*)B + (size_t)(tn * 64 + l16) * K + quad * 8;

    f32x4 acc[4] = {{0.f,0.f,0.f,0.f},{0.f,0.f,0.f,0.f},
                    {0.f,0.f,0.f,0.f},{0.f,0.f,0.f,0.f}};
    for (int k = 0; k < K; k += 32) {
        bf16x8 av = *(const bf16x8*)(a_ptr + k);
#pragma unroll
        for (int t = 0; t < 4; ++t) {
            bf16x8 bv = *(const bf16x8*)(b_ptr + (size_t)t * 16 * K + k);
            acc[t] = MFMA16(av, bv, acc[t]);
        }
    }
#pragma unroll
    for (int t = 0; t < 4; ++t)
#pragma unroll
        for (int r = 0; r < 4; ++r)
            C[(size_t)(tm * 16 + quad * 4 + r) * N + tn * 64 + t * 16 + l16] =
                __float2bfloat16(acc[t][r] * scale);
}

// fp32-input fallback (ws too small): converts in-loop (validated R3 path)
__device__ inline bf16x8 cvt8(const float* p) {
    float4 a = *(const float4*)p;
    float4 b = *(const float4*)(p + 4);
    bf16x8 r;
    r[0] = (__bf16)a.x; r[1] = (__bf16)a.y; r[2] = (__bf16)a.z; r[3] = (__bf16)a.w;
    r[4] = (__bf16)b.x; r[5] = (__bf16)b.y; r[6] = (__bf16)b.z; r[7] = (__bf16)b.w;
    return r;
}
__global__ __launch_bounds__(256) void gemm_bt_f32(const float* __restrict__ A,
                                                   const float* __restrict__ B,
                                                   __hip_bfloat16* __restrict__ C,
                                                   int M, int N, int K, float scale) {
    int wave = blockIdx.x * 4 + (threadIdx.x >> 6);
    int lane = threadIdx.x & 63;
    int tilesN = N >> 6;
    int tm = wave / tilesN, tn = wave - tm * tilesN;
    int quad = lane >> 4, l16 = lane & 15;
    const float* a_ptr = A + (size_t)(tm * 16 + l16) * K + quad * 8;
    const float* b_ptr = B + (size_t)(tn * 64 + l16) * K + quad * 8;
    f32x4 acc[4] = {{0.f,0.f,0.f,0.f},{0.f,0.f,0.f,0.f},
                    {0.f,0.f,0.f,0.f},{0.f,0.f,0.f,0.f}};
    for (int k = 0; k < K; k += 32) {
        bf16x8 av = cvt8(a_ptr + k);
#pragma unroll
        for (int t = 0; t < 4; ++t)
            acc[t] = MFMA16(av, cvt8(b_ptr + (size_t)t * 16 * K + k), acc[t]);
    }
#pragma unroll
    for (int t = 0; t < 4; ++t)
#pragma unroll
        for (int r = 0; r < 4; ++r)
            C[(size_t)(tm * 16 + quad * 4 + r) * N + tn * 64 + t * 16 + l16] =
                __float2bfloat16(acc[t][r] * scale);
}

// ---------------------------------------------------------------------------
// MFMA flash attention. Block = (b, g, 32-row q-block); 4 waves = 4 heads of
// the group sharing K (row-major LDS) and V (transposed LDS) tiles of 64 keys.
// Wave: S^T = K·Q^T (16x16x32 MFMA), online softmax in C-layout, P->LDS
// round-trip (A-layout), O += P·V with V^T b-frags. Q pre-scaled by hd^-0.5.
// ---------------------------------------------------------------------------
__global__ __launch_bounds__(256) void attn_mfma(const __hip_bfloat16* __restrict__ Q,
                                                 const __hip_bfloat16* __restrict__ Kb,
                                                 const __hip_bfloat16* __restrict__ Vb,
                                                 float* __restrict__ O) {
    const int T = 2048, DKV = 512, HD = 128, CM = 2048;
    __shared__ __bf16 Ks[64][136];    // 64 keys x 128 d, pad 8 (stride 68 dw = 2-way)
    __shared__ __bf16 Vt[128][88];    // transposed: 128 d x 64 keys, pad 24
    __shared__ __bf16 Pl[4][32][88];  // per-wave P: 32 q x 64 keys

    int tid = threadIdx.x;
    int wave = tid >> 6, lane = tid & 63;
    int quad = lane >> 4, l16 = lane & 15;

    int bg = blockIdx.x & 7;          // (b,g) spread across XCDs
    int slot = blockIdx.x >> 3;       // 0..63 -> qb pairing heavy+light per CU
    int qb = (slot < 32) ? (63 - slot) : (slot - 32);
    int b = bg >> 2, g = bg & 3;
    int h = g * 4 + wave;             // each wave = one head of the group
    int q0 = qb * 32;

    // Q b-frags in registers: [nt][dt], lane reads Q[q0+nt*16+l16][dt*32+quad*8]
    bf16x8 qf[2][4];
    const __bf16* qbase = (const __bf16*)Q + (size_t)b * T * CM + (size_t)h * HD;
#pragma unroll
    for (int nt = 0; nt < 2; ++nt)
#pragma unroll
        for (int dt = 0; dt < 4; ++dt)
            qf[nt][dt] = *(const bf16x8*)(qbase + (size_t)(q0 + nt * 16 + l16) * CM
                                          + dt * 32 + quad * 8);

    float m_r[2] = {-1e30f, -1e30f};
    float l_r[2] = {0.f, 0.f};
    f32x4 o_acc[2][8];
#pragma unroll
    for (int mt = 0; mt < 2; ++mt)
#pragma unroll
        for (int nto = 0; nto < 8; ++nto)
            o_acc[mt][nto] = f32x4{0.f, 0.f, 0.f, 0.f};

    const __bf16* kgbase = (const __bf16*)Kb + (size_t)b * T * DKV + g * HD;
    const __bf16* vgbase = (const __bf16*)Vb + (size_t)b * T * DKV + g * HD;

    int nch = (qb >> 1) + 1;
    for (int ch = 0; ch < nch; ++ch) {
        int j0 = ch * 64;
        __syncthreads();
        // --- stage K chunk (row copy, b128) ---
        {
            int key = tid >> 2, c0 = tid & 3;
            const __bf16* src = kgbase + (size_t)(j0 + key) * DKV;
#pragma unroll
            for (int i = 0; i < 4; ++i) {
                int c = c0 * 4 + i;
                *(bf16x8*)&Ks[key][c * 8] = *(const bf16x8*)(src + c * 8);
            }
        }
        // --- stage V transposed (2 keys/thread, packed dword writes) ---
        {
            int k2 = tid & 31, d8 = tid >> 5;
            const __bf16* s0 = vgbase + (size_t)(j0 + 2 * k2) * DKV;
            const __bf16* s1 = s0 + DKV;
#pragma unroll
            for (int i = 0; i < 2; ++i) {
                int dbase = i * 64 + d8 * 8;
                union { bf16x8 v; unsigned short u[8]; } v0, v1;
                v0.v = *(const bf16x8*)(s0 + dbase);
                v1.v = *(const bf16x8*)(s1 + dbase);
#pragma unroll
                for (int j = 0; j < 8; ++j)
                    *(unsigned int*)&Vt[dbase + j][2 * k2] =
                        ((unsigned int)v1.u[j] << 16) | v0.u[j];
            }
        }
        __syncthreads();

        // --- S^T = K · Q^T : st[nt][t], C-layout col=q(l16), row=key(quad*4+r)
        f32x4 st[2][4];
#pragma unroll
        for (int nt = 0; nt < 2; ++nt)
#pragma unroll
            for (int t = 0; t < 4; ++t)
                st[nt][t] = f32x4{0.f, 0.f, 0.f, 0.f};
#pragma unroll
        for (int t = 0; t < 4; ++t)
#pragma unroll
            for (int dt = 0; dt < 4; ++dt) {
                bf16x8 kf = *(const bf16x8*)&Ks[t * 16 + l16][dt * 32 + quad * 8];
                st[0][t] = MFMA16(kf, qf[0][dt], st[0][t]);
                st[1][t] = MFMA16(kf, qf[1][dt], st[1][t]);
            }

        // --- mask + online softmax (per nt), write P to LDS in A-layout rows
        float alpha[2];
#pragma unroll
        for (int nt = 0; nt < 2; ++nt) {
            int qg = q0 + nt * 16 + l16;
            float cmax = -1e30f;
#pragma unroll
            for (int t = 0; t < 4; ++t)
#pragma unroll
                for (int r = 0; r < 4; ++r) {
                    int kg = j0 + t * 16 + quad * 4 + r;
                    float s = (kg <= qg) ? st[nt][t][r] : -1e30f;
                    st[nt][t][r] = s;
                    cmax = fmaxf(cmax, s);
                }
            cmax = fmaxf(cmax, __shfl_xor(cmax, 16));
            cmax = fmaxf(cmax, __shfl_xor(cmax, 32));
            float mnew = fmaxf(m_r[nt], cmax);
            alpha[nt] = __expf(m_r[nt] - mnew);
            m_r[nt] = mnew;
            float ps = 0.f;
#pragma unroll
            for (int t = 0; t < 4; ++t) {
                float p0 = __expf(st[nt][t][0] - mnew);
                float p1 = __expf(st[nt][t][1] - mnew);
                float p2 = __expf(st[nt][t][2] - mnew);
                float p3 = __expf(st[nt][t][3] - mnew);
                ps += (p0 + p1) + (p2 + p3);
                *(unsigned int*)&Pl[wave][nt * 16 + l16][t * 16 + quad * 4]     = pack_bf16(p0, p1);
                *(unsigned int*)&Pl[wave][nt * 16 + l16][t * 16 + quad * 4 + 2] = pack_bf16(p2, p3);
            }
            ps += __shfl_xor(ps, 16);
            ps += __shfl_xor(ps, 32);
            l_r[nt] = l_r[nt] * alpha[nt] + ps;
        }

        // --- rescale O by alpha (redistribute q: l16 -> quad*4+r) ---
#pragma unroll
        for (int mt = 0; mt < 2; ++mt)
#pragma unroll
            for (int r = 0; r < 4; ++r) {
                float alr = __shfl(alpha[mt], quad * 4 + r);
#pragma unroll
                for (int nto = 0; nto < 8; ++nto)
                    o_acc[mt][nto][r] *= alr;
            }

        // --- O += P · V : a-frag from Pl, b-frag from Vt ---
#pragma unroll
        for (int mt = 0; mt < 2; ++mt)
#pragma unroll
            for (int kk = 0; kk < 2; ++kk) {
                bf16x8 pf = *(const bf16x8*)&Pl[wave][mt * 16 + l16][kk * 32 + quad * 8];
#pragma unroll
                for (int nto = 0; nto < 8; ++nto) {
                    bf16x8 vf = *(const bf16x8*)&Vt[nto * 16 + l16][kk * 32 + quad * 8];
                    o_acc[mt][nto] = MFMA16(pf, vf, o_acc[mt][nto]);
                }
            }
    }

    // --- epilogue: O * (1/l), fp32 store ---
    float* obase = O + (size_t)b * T * CM + (size_t)h * HD;
#pragma unroll
    for (int mt = 0; mt < 2; ++mt) {
        float invl = 1.f / l_r[mt];
#pragma unroll
        for (int r = 0; r < 4; ++r) {
            float ir = __shfl(invl, quad * 4 + r);
            float* orow = obase + (size_t)(q0 + 16 * mt + quad * 4 + r) * CM;
#pragma unroll
            for (int nto = 0; nto < 8; ++nto)
                orow[nto * 16 + l16] = o_acc[mt][nto][r] * ir;
        }
    }
}

extern "C" void kernel_launch(void* const* d_in, const int* in_sizes, int n_in,
                              void* d_out, int out_size, void* d_ws, size_t ws_size,
                              hipStream_t stream) {
    const float* x  = (const float*)d_in[0];   // [2,2048,2048]
    const float* Wq = (const float*)d_in[1];   // [2048,2048]
    const float* Wk = (const float*)d_in[2];   // [512,2048]
    const float* Wv = (const float*)d_in[3];   // [512,2048]
    float* out = (float*)d_out;

    const int M = 4096, Kd = 2048;
    const float qscale = 0.08838834764831845f;  // 128^-0.5 folded into Q proj

    if (ws_size >= 54525952ull) {
        __hip_bfloat16* xb  = (__hip_bfloat16*)d_ws;         // 8M elem
        __hip_bfloat16* Wqb = xb + 8388608;                  // 4M
        __hip_bfloat16* Wkb = Wqb + 4194304;                 // 1M
        __hip_bfloat16* Wvb = Wkb + 1048576;                 // 1M
        __hip_bfloat16* Qb  = Wvb + 1048576;                 // 8M
        __hip_bfloat16* Kbf = Qb + 8388608;                  // 2M
        __hip_bfloat16* Vbf = Kbf + 2097152;                 // 2M

        cvt_f32_bf16<<<4096, 256, 0, stream>>>(x,  xb,  8388608);
        cvt_f32_bf16<<<2048, 256, 0, stream>>>(Wq, Wqb, 4194304);
        cvt_f32_bf16<<< 512, 256, 0, stream>>>(Wk, Wkb, 1048576);
        cvt_f32_bf16<<< 512, 256, 0, stream>>>(Wv, Wvb, 1048576);

        gemm_bt_bf16<<<2048, 256, 0, stream>>>(xb, Wqb, Qb,  M, 2048, Kd, qscale);
        gemm_bt_bf16<<< 512, 256, 0, stream>>>(xb, Wkb, Kbf, M,  512, Kd, 1.f);
        gemm_bt_bf16<<< 512, 256, 0, stream>>>(xb, Wvb, Vbf, M,  512, Kd, 1.f);

        attn_mfma<<<512, 256, 0, stream>>>(Qb, Kbf, Vbf, out);
    } else {
        __hip_bfloat16* Qb  = (__hip_bfloat16*)d_ws;
        __hip_bfloat16* Kbf = Qb + 8388608;
        __hip_bfloat16* Vbf = Kbf + 2097152;

        gemm_bt_f32<<<2048, 256, 0, stream>>>(x, Wq, Qb,  M, 2048, Kd, qscale);
        gemm_bt_f32<<< 512, 256, 0, stream>>>(x, Wk, Kbf, M,  512, Kd, 1.f);
        gemm_bt_f32<<< 512, 256, 0, stream>>>(x, Wv, Vbf, M,  512, Kd, 1.f);

        attn_mfma<<<512, 256, 0, stream>>>(Qb, Kbf, Vbf, out);
    }
}

// Round 5
// 337.138 us; speedup vs baseline: 13.3015x; 1.9822x over previous
//
#include <hip/hip_runtime.h>
#include <hip/hip_bf16.h>

typedef __bf16 bf16x8 __attribute__((ext_vector_type(8)));
typedef float f32x4 __attribute__((ext_vector_type(4)));

#define MFMA16(a, b, c) __builtin_amdgcn_mfma_f32_16x16x32_bf16(a, b, c, 0, 0, 0)

__device__ inline unsigned int pack_bf16(float a, float b) {
    unsigned short ua = __builtin_bit_cast(unsigned short, (__bf16)a);
    unsigned short ub = __builtin_bit_cast(unsigned short, (__bf16)b);
    return ((unsigned int)ub << 16) | ua;
}

// ---------------------------------------------------------------------------
// fp32 -> bf16 conversion (each element converted exactly once)
// ---------------------------------------------------------------------------
__global__ void cvt_f32_bf16(const float* __restrict__ in,
                             __hip_bfloat16* __restrict__ out, int n) {
    int i = (blockIdx.x * blockDim.x + threadIdx.x) * 8;
    if (i >= n) return;
    float4 a = *(const float4*)(in + i);
    float4 b = *(const float4*)(in + i + 4);
    bf16x8 r;
    r[0] = (__bf16)a.x; r[1] = (__bf16)a.y; r[2] = (__bf16)a.z; r[3] = (__bf16)a.w;
    r[4] = (__bf16)b.x; r[5] = (__bf16)b.y; r[6] = (__bf16)b.z; r[7] = (__bf16)b.w;
    *(bf16x8*)((__bf16*)out + i) = r;
}

// ---------------------------------------------------------------------------
// 128xBN-tile GEMM, C = scale * A · B^T.  A:[M,K] B:[N,K] bf16 row-major.
// LDS staged via global_load_lds(16B) with FRAGMENT-ORDER layout:
//   frag-block fb (1 KB) holds element [row = fb*16 + (lane&15)][k = (lane>>4)*8 + j]
//   at offset fb*1024 + lane*16  ->  staging writes (HW: base+lane*16) AND
//   fragment ds_read_b128 are both lane-linear => zero bank conflicts.
// 4 waves in 2x2 over the tile; each wave: 64 x BN/2, acc 4 x BN/32 MFMA tiles.
// Epilogue routes columns >= split to C1 (fused K/V projection).
// ---------------------------------------------------------------------------
template <int BN>
__global__ __launch_bounds__(256) void gemm_tile(const __bf16* __restrict__ A,
                                                 const __bf16* __restrict__ B,
                                                 __bf16* __restrict__ C0,
                                                 __bf16* __restrict__ C1,
                                                 int K, int tilesN, int split, int ldc,
                                                 float scale) {
    constexpr int BBLK = BN / 16;           // B frag-blocks
    constexpr int JT = BN / 32;             // b-tiles per wave
    __shared__ __bf16 As[8 * 512];          // 8 KB
    __shared__ __bf16 Bs[BBLK * 512];

    int tid = threadIdx.x;
    int wave = tid >> 6, lane = tid & 63;
    int quad = lane >> 4, l16 = lane & 15;

    int tm = blockIdx.x / tilesN, tn = blockIdx.x % tilesN;

    const __bf16* Abase = A + (size_t)tm * 128 * K + (size_t)l16 * K + quad * 8;
    const __bf16* Bbase = B + (size_t)tn * BN * K + (size_t)l16 * K + quad * 8;

    f32x4 acc[4][JT];
#pragma unroll
    for (int i = 0; i < 4; ++i)
#pragma unroll
        for (int j = 0; j < JT; ++j)
            acc[i][j] = f32x4{0.f, 0.f, 0.f, 0.f};

    for (int kt = 0; kt < K; kt += 32) {
        if (kt) __syncthreads();
#pragma unroll
        for (int rr = 0; rr < 2; ++rr) {           // A: 8 frag-blocks
            int fb = rr * 4 + wave;
            __builtin_amdgcn_global_load_lds(
                (const __attribute__((address_space(1))) unsigned int*)(Abase + (size_t)fb * 16 * K + kt),
                (__attribute__((address_space(3))) unsigned int*)(As + fb * 512 + lane * 8),
                16, 0, 0);
        }
#pragma unroll
        for (int rr = 0; rr < BBLK / 4; ++rr) {    // B: BBLK frag-blocks
            int fb = rr * 4 + wave;
            __builtin_amdgcn_global_load_lds(
                (const __attribute__((address_space(1))) unsigned int*)(Bbase + (size_t)fb * 16 * K + kt),
                (__attribute__((address_space(3))) unsigned int*)(Bs + fb * 512 + lane * 8),
                16, 0, 0);
        }
        __syncthreads();

        bf16x8 af[4], bfr[JT];
#pragma unroll
        for (int i = 0; i < 4; ++i)
            af[i] = *(const bf16x8*)(As + ((wave >> 1) * 4 + i) * 512 + lane * 8);
#pragma unroll
        for (int j = 0; j < JT; ++j)
            bfr[j] = *(const bf16x8*)(Bs + ((wave & 1) * (BBLK / 2) + j) * 512 + lane * 8);
#pragma unroll
        for (int i = 0; i < 4; ++i)
#pragma unroll
            for (int j = 0; j < JT; ++j)
                acc[i][j] = MFMA16(af[i], bfr[j], acc[i][j]);
    }

    // epilogue: C/D layout col=l16, row=quad*4+r
    int colbase = tn * BN + (wave & 1) * (BN / 2);
#pragma unroll
    for (int i = 0; i < 4; ++i) {
        int row = tm * 128 + (wave >> 1) * 64 + i * 16 + quad * 4;
#pragma unroll
        for (int j = 0; j < JT; ++j) {
            int col = colbase + j * 16 + l16;
            __bf16* Cw = (col < split) ? C0 : C1;
            int c = (col < split) ? col : col - split;
#pragma unroll
            for (int r = 0; r < 4; ++r)
                Cw[(size_t)(row + r) * ldc + c] = (__bf16)(acc[i][j][r] * scale);
        }
    }
}

// ---------------------------------------------------------------------------
// MFMA flash attention (unchanged from R4). Block = (b, g, 32-row q-block);
// 4 waves = 4 heads sharing K/V LDS tiles of 64 keys.
// ---------------------------------------------------------------------------
__global__ __launch_bounds__(256) void attn_mfma(const __hip_bfloat16* __restrict__ Q,
                                                 const __hip_bfloat16* __restrict__ Kb,
                                                 const __hip_bfloat16* __restrict__ Vb,
                                                 float* __restrict__ O) {
    const int T = 2048, DKV = 512, HD = 128, CM = 2048;
    __shared__ __bf16 Ks[64][136];
    __shared__ __bf16 Vt[128][88];
    __shared__ __bf16 Pl[4][32][88];

    int tid = threadIdx.x;
    int wave = tid >> 6, lane = tid & 63;
    int quad = lane >> 4, l16 = lane & 15;

    int bg = blockIdx.x & 7;
    int slot = blockIdx.x >> 3;
    int qb = (slot < 32) ? (63 - slot) : (slot - 32);
    int b = bg >> 2, g = bg & 3;
    int h = g * 4 + wave;
    int q0 = qb * 32;

    bf16x8 qf[2][4];
    const __bf16* qbase = (const __bf16*)Q + (size_t)b * T * CM + (size_t)h * HD;
#pragma unroll
    for (int nt = 0; nt < 2; ++nt)
#pragma unroll
        for (int dt = 0; dt < 4; ++dt)
            qf[nt][dt] = *(const bf16x8*)(qbase + (size_t)(q0 + nt * 16 + l16) * CM
                                          + dt * 32 + quad * 8);

    float m_r[2] = {-1e30f, -1e30f};
    float l_r[2] = {0.f, 0.f};
    f32x4 o_acc[2][8];
#pragma unroll
    for (int mt = 0; mt < 2; ++mt)
#pragma unroll
        for (int nto = 0; nto < 8; ++nto)
            o_acc[mt][nto] = f32x4{0.f, 0.f, 0.f, 0.f};

    const __bf16* kgbase = (const __bf16*)Kb + (size_t)b * T * DKV + g * HD;
    const __bf16* vgbase = (const __bf16*)Vb + (size_t)b * T * DKV + g * HD;

    int nch = (qb >> 1) + 1;
    for (int ch = 0; ch < nch; ++ch) {
        int j0 = ch * 64;
        __syncthreads();
        {
            int key = tid >> 2, c0 = tid & 3;
            const __bf16* src = kgbase + (size_t)(j0 + key) * DKV;
#pragma unroll
            for (int i = 0; i < 4; ++i) {
                int c = c0 * 4 + i;
                *(bf16x8*)&Ks[key][c * 8] = *(const bf16x8*)(src + c * 8);
            }
        }
        {
            int k2 = tid & 31, d8 = tid >> 5;
            const __bf16* s0 = vgbase + (size_t)(j0 + 2 * k2) * DKV;
            const __bf16* s1 = s0 + DKV;
#pragma unroll
            for (int i = 0; i < 2; ++i) {
                int dbase = i * 64 + d8 * 8;
                union { bf16x8 v; unsigned short u[8]; } v0, v1;
                v0.v = *(const bf16x8*)(s0 + dbase);
                v1.v = *(const bf16x8*)(s1 + dbase);
#pragma unroll
                for (int j = 0; j < 8; ++j)
                    *(unsigned int*)&Vt[dbase + j][2 * k2] =
                        ((unsigned int)v1.u[j] << 16) | v0.u[j];
            }
        }
        __syncthreads();

        f32x4 st[2][4];
#pragma unroll
        for (int nt = 0; nt < 2; ++nt)
#pragma unroll
            for (int t = 0; t < 4; ++t)
                st[nt][t] = f32x4{0.f, 0.f, 0.f, 0.f};
#pragma unroll
        for (int t = 0; t < 4; ++t)
#pragma unroll
            for (int dt = 0; dt < 4; ++dt) {
                bf16x8 kf = *(const bf16x8*)&Ks[t * 16 + l16][dt * 32 + quad * 8];
                st[0][t] = MFMA16(kf, qf[0][dt], st[0][t]);
                st[1][t] = MFMA16(kf, qf[1][dt], st[1][t]);
            }

        float alpha[2];
#pragma unroll
        for (int nt = 0; nt < 2; ++nt) {
            int qg = q0 + nt * 16 + l16;
            float cmax = -1e30f;
#pragma unroll
            for (int t = 0; t < 4; ++t)
#pragma unroll
                for (int r = 0; r < 4; ++r) {
                    int kg = j0 + t * 16 + quad * 4 + r;
                    float s = (kg <= qg) ? st[nt][t][r] : -1e30f;
                    st[nt][t][r] = s;
                    cmax = fmaxf(cmax, s);
                }
            cmax = fmaxf(cmax, __shfl_xor(cmax, 16));
            cmax = fmaxf(cmax, __shfl_xor(cmax, 32));
            float mnew = fmaxf(m_r[nt], cmax);
            alpha[nt] = __expf(m_r[nt] - mnew);
            m_r[nt] = mnew;
            float ps = 0.f;
#pragma unroll
            for (int t = 0; t < 4; ++t) {
                float p0 = __expf(st[nt][t][0] - mnew);
                float p1 = __expf(st[nt][t][1] - mnew);
                float p2 = __expf(st[nt][t][2] - mnew);
                float p3 = __expf(st[nt][t][3] - mnew);
                ps += (p0 + p1) + (p2 + p3);
                *(unsigned int*)&Pl[wave][nt * 16 + l16][t * 16 + quad * 4]     = pack_bf16(p0, p1);
                *(unsigned int*)&Pl[wave][nt * 16 + l16][t * 16 + quad * 4 + 2] = pack_bf16(p2, p3);
            }
            ps += __shfl_xor(ps, 16);
            ps += __shfl_xor(ps, 32);
            l_r[nt] = l_r[nt] * alpha[nt] + ps;
        }

#pragma unroll
        for (int mt = 0; mt < 2; ++mt)
#pragma unroll
            for (int r = 0; r < 4; ++r) {
                float alr = __shfl(alpha[mt], quad * 4 + r);
#pragma unroll
                for (int nto = 0; nto < 8; ++nto)
                    o_acc[mt][nto][r] *= alr;
            }

#pragma unroll
        for (int mt = 0; mt < 2; ++mt)
#pragma unroll
            for (int kk = 0; kk < 2; ++kk) {
                bf16x8 pf = *(const bf16x8*)&Pl[wave][mt * 16 + l16][kk * 32 + quad * 8];
#pragma unroll
                for (int nto = 0; nto < 8; ++nto) {
                    bf16x8 vf = *(const bf16x8*)&Vt[nto * 16 + l16][kk * 32 + quad * 8];
                    o_acc[mt][nto] = MFMA16(pf, vf, o_acc[mt][nto]);
                }
            }
    }

    float* obase = O + (size_t)b * T * CM + (size_t)h * HD;
#pragma unroll
    for (int mt = 0; mt < 2; ++mt) {
        float invl = 1.f / l_r[mt];
#pragma unroll
        for (int r = 0; r < 4; ++r) {
            float ir = __shfl(invl, quad * 4 + r);
            float* orow = obase + (size_t)(q0 + 16 * mt + quad * 4 + r) * CM;
#pragma unroll
            for (int nto = 0; nto < 8; ++nto)
                orow[nto * 16 + l16] = o_acc[mt][nto][r] * ir;
        }
    }
}

extern "C" void kernel_launch(void* const* d_in, const int* in_sizes, int n_in,
                              void* d_out, int out_size, void* d_ws, size_t ws_size,
                              hipStream_t stream) {
    const float* x  = (const float*)d_in[0];   // [2,2048,2048]
    const float* Wq = (const float*)d_in[1];   // [2048,2048]
    const float* Wk = (const float*)d_in[2];   // [512,2048]
    const float* Wv = (const float*)d_in[3];   // [512,2048]
    float* out = (float*)d_out;

    const float qscale = 0.08838834764831845f;  // 128^-0.5 folded into Q proj

    __hip_bfloat16* xb  = (__hip_bfloat16*)d_ws;         // 8M elem
    __hip_bfloat16* Wqb = xb + 8388608;                  // 4M
    __hip_bfloat16* Wkb = Wqb + 4194304;                 // 1M  (Wkb+Wvb = [1024][2048])
    __hip_bfloat16* Wvb = Wkb + 1048576;                 // 1M
    __hip_bfloat16* Qb  = Wvb + 1048576;                 // 8M
    __hip_bfloat16* Kbf = Qb + 8388608;                  // 2M
    __hip_bfloat16* Vbf = Kbf + 2097152;                 // 2M

    cvt_f32_bf16<<<4096, 256, 0, stream>>>(x,  xb,  8388608);
    cvt_f32_bf16<<<2048, 256, 0, stream>>>(Wq, Wqb, 4194304);
    cvt_f32_bf16<<< 512, 256, 0, stream>>>(Wk, Wkb, 1048576);
    cvt_f32_bf16<<< 512, 256, 0, stream>>>(Wv, Wvb, 1048576);

    // Q projection: M=4096, N=2048 -> 32x16 = 512 blocks of 128x128
    gemm_tile<128><<<512, 256, 0, stream>>>((const __bf16*)xb, (const __bf16*)Wqb,
                                            (__bf16*)Qb, (__bf16*)Qb,
                                            2048, 16, 1 << 30, 2048, qscale);
    // fused K+V projection: N=1024 -> 32x16 = 512 blocks of 128x64, split at 512
    gemm_tile<64><<<512, 256, 0, stream>>>((const __bf16*)xb, (const __bf16*)Wkb,
                                           (__bf16*)Kbf, (__bf16*)Vbf,
                                           2048, 16, 512, 512, 1.f);

    attn_mfma<<<512, 256, 0, stream>>>(Qb, Kbf, Vbf, out);
}